// Round 11
// baseline (122.476 us; speedup 1.0000x reference)
//
#include <hip/hip_runtime.h>
#include <math.h>

#define NFFT   1024
#define HOP    256
#define NBANDS 128
#define TFRM   1001
#define BB     16
#define NLEN   256000   // (T-1)*HOP
#define PADL   512
#define NPAIRS 501      // frame pairs per batch
#define QPB    126      // 4-pair (8-frame) blocks per batch: ceil(501/4)

// padded LDS index in float2 units: +1 every 16 breaks radix-4 scatter conflicts
#define PX(a) ((a) + ((a) >> 4))

// ---- fused zeroing + table init ----
// ws[0..511] = interleaved (cos,sin) of exp(-2*pi*i*k/1024); ws[512..1535] =
// Hann*(1/1024).
__global__ __launch_bounds__(256) void zero_and_tables(
    float4* __restrict__ out4, int n4, float* __restrict__ ws)
{
    const int tid = blockIdx.x * 256 + threadIdx.x;
    const float4 z = make_float4(0.0f, 0.0f, 0.0f, 0.0f);
    for (int i = tid; i < n4; i += gridDim.x * 256) out4[i] = z;
    if (tid < 256) {
        float s_, c_;
        sincosf(-6.283185307179586f * (float)tid * (1.0f / 1024.0f), &s_, &c_);
        ws[2 * tid]     = c_;
        ws[2 * tid + 1] = s_;
    } else if (tid < 1280) {
        const int k = tid - 256;
        ws[512 + k] = 0.5f * (1.0f - cosf(6.283185307179586f * (float)k * (1.0f / 1023.0f)))
                      * (1.0f / 1024.0f);
    }
}

// One Stockham radix-4 stage on float2 (re,im) LDS data.
// SGN=-1 forward, +1 inverse (conjugate twiddles, +i).
template<int NS, int SGN>
__device__ __forceinline__ void r4stage2(const float2* __restrict__ x,
                                         float2* __restrict__ y,
                                         const float2* __restrict__ tw, int j) {
    const int m = j & (NS - 1);
    const float2 a0 = x[PX(j)];
    const float2 a1 = x[PX(j + 256)];
    const float2 a2 = x[PX(j + 512)];
    const float2 a3 = x[PX(j + 768)];
    float v1r, v1i, v2r, v2i, v3r, v3i;
    {
        const float2 w = tw[m * (256 / NS)];
        const float wr1 = w.x, wi1 = (SGN < 0) ? w.y : -w.y;
        const float wr2 = wr1 * wr1 - wi1 * wi1, wi2 = 2.0f * wr1 * wi1;
        const float wr3 = wr2 * wr1 - wi2 * wi1, wi3 = wr2 * wi1 + wi2 * wr1;
        v1r = a1.x * wr1 - a1.y * wi1; v1i = a1.x * wi1 + a1.y * wr1;
        v2r = a2.x * wr2 - a2.y * wi2; v2i = a2.x * wi2 + a2.y * wr2;
        v3r = a3.x * wr3 - a3.y * wi3; v3i = a3.x * wi3 + a3.y * wr3;
    }
    const float t0r = a0.x + v2r, t0i = a0.y + v2i;
    const float t1r = a0.x - v2r, t1i = a0.y - v2i;
    const float t2r = v1r + v3r,  t2i = v1i + v3i;
    const float ur  = v1r - v3r,  ui  = v1i - v3i;
    const float t3r = (SGN < 0) ? ui  : -ui;
    const float t3i = (SGN < 0) ? -ur : ur;
    const int d = ((j & ~(NS - 1)) << 2) + m;
    y[PX(d)]          = make_float2(t0r + t2r, t0i + t2i);
    y[PX(d + NS)]     = make_float2(t1r + t3r, t1i + t3i);
    y[PX(d + 2*NS)]   = make_float2(t0r - t2r, t0i - t2i);
    y[PX(d + 3*NS)]   = make_float2(t1r - t3r, t1i - t3i);
}

// ---- main kernel: one block (256 threads) per 8 FRAMES (4 pairs, sequential) ----
// Register OLA accumulator s[11]: frame f sample k=tid+256c -> block slot f+c.
// Residue classes mod 8: slots 3..7 are block-complete (4/4 contributions) ->
// plain stores; slots {0,1,2,8,9,10} shared with ONE neighbor -> atomics.
// Store-residues {3..7} and atomic-residues {0,1,2} are globally disjoint.
// XCD-chunked swizzle: 2016 = 8 XCDs x 252 (= 2 whole batches per XCD).
__global__ __launch_bounds__(256, 8) void fn_kernel(
    const float* __restrict__ fb,     // (B, 1, 128, T)
    const float* __restrict__ noise,  // (B, 1, NLEN)
    const float* __restrict__ tbl,    // d_ws tables from zero_and_tables
    float* __restrict__ out)          // (B, 1, NLEN), pre-zeroed
{
    __shared__ float2 b0[1087], b1[1087];   // PX(1023)=1086
    __shared__ float2 tw[256];
    __shared__ float2 gab[128];             // (ga, gb) for current pair

    const int tid = threadIdx.x;
    const int hw  = blockIdx.x;
    const int blk = (hw & 7) * 252 + (hw >> 3);   // bijective: 2016 = 8*252
    const int b   = blk / QPB;
    const int q   = blk - b * QPB;                // 8-frame group within batch
    // interior block: all 4 pairs have in-bounds taps AND all 11 OLA slots
    // in-bounds (q>=1 -> min pos 1536; q<=123 -> max pos 254207 < 256000)
    const bool blk_interior = (q >= 1) & (q <= 123);

    tw[tid] = ((const float2*)tbl)[tid & 255];
    const float* nb  = noise + (size_t)b * NLEN;
    const float* win = tbl + 512;
    const int base_blk = 2048 * q - PADL;

    // window values are pp-invariant: hoist
    float wv[4];
    #pragma unroll
    for (int c = 0; c < 4; ++c) wv[c] = win[tid + 256 * c];

    float s[11];
    #pragma unroll
    for (int i = 0; i < 11; ++i) s[i] = 0.0f;

    #pragma unroll
    for (int pp = 0; pp < 4; ++pp) {
        const int p = 4 * q + pp;
        if (p < NPAIRS) {                    // block-uniform guard
            const int  ta    = 2 * p;
            const bool has_b = (ta + 1) < TFRM;
            const bool pint  = (p >= 1) & (p <= 498);

            // protect b0 (prev pair's final reads) + gab (prev Hermitian reads)
            __syncthreads();
            if (tid < NBANDS) {
                const size_t off = (size_t)b * (NBANDS * TFRM) + (size_t)tid * TFRM + ta;
                const float ga_ = fb[off];
                const float gb_ = has_b ? fb[off + 1] : 0.0f;
                gab[tid] = make_float2(ga_, gb_);
            }

            // ---- fused global load + forward stage 0 (NS=1) ----
            const int base = ta * HOP - PADL;
            float2 a0, a1, a2, a3;
            if (pint) {
                // taps 256 apart == HOP: frame_b reuses frame_a's next tap
                const int g = base + tid;
                const float v0 = __builtin_fmaf(nb[g],        2.0f, -1.0f);
                const float v1 = __builtin_fmaf(nb[g + 256],  2.0f, -1.0f);
                const float v2 = __builtin_fmaf(nb[g + 512],  2.0f, -1.0f);
                const float v3 = __builtin_fmaf(nb[g + 768],  2.0f, -1.0f);
                const float v4 = __builtin_fmaf(nb[g + 1024], 2.0f, -1.0f);
                a0 = make_float2(v0, v1);
                a1 = make_float2(v1, v2);
                a2 = make_float2(v2, v3);
                a3 = make_float2(v3, v4);
            } else {
                const int g = base + tid;
                #define LD2(gg) make_float2( \
                    ((gg) >= 0 && (gg) < NLEN) ? nb[(gg)] * 2.0f - 1.0f : 0.0f, \
                    (has_b && (gg) + HOP >= 0 && (gg) + HOP < NLEN) ? nb[(gg) + HOP] * 2.0f - 1.0f : 0.0f)
                a0 = LD2(g); a1 = LD2(g + 256); a2 = LD2(g + 512); a3 = LD2(g + 768);
                #undef LD2
            }
            {
                const float t0r = a0.x + a2.x, t0i = a0.y + a2.y;
                const float t1r = a0.x - a2.x, t1i = a0.y - a2.y;
                const float t2r = a1.x + a3.x, t2i = a1.y + a3.y;
                const float ur  = a1.x - a3.x, ui  = a1.y - a3.y;
                const float t3r = ui, t3i = -ur;           // -i*u (forward)
                const int d = 4 * tid;
                b0[PX(d)]     = make_float2(t0r + t2r, t0i + t2i);
                b0[PX(d + 1)] = make_float2(t1r + t3r, t1i + t3i);
                b0[PX(d + 2)] = make_float2(t0r - t2r, t0i - t2i);
                b0[PX(d + 3)] = make_float2(t1r - t3r, t1i - t3i);
            }
            __syncthreads();

            // ---- forward stages NS=4..256 ----
            r4stage2<4,   -1>(b0, b1, tw, tid); __syncthreads();
            r4stage2<16,  -1>(b1, b0, tw, tid); __syncthreads();
            r4stage2<64,  -1>(b0, b1, tw, tid); __syncthreads();
            r4stage2<256, -1>(b1, b0, tw, tid); __syncthreads();
            // Z in b0, natural order

            // ---- fused Hermitian unpack + filter + inverse stage 0 (NS=1) ----
            // W[k]=ga*Fa+i*gb*Fb; Fa=(Z[k]+conj(Z[N-k]))/2, Fb=-i(Z[k]-conj(Z[N-k]))/2
            // No barrier between b0-reads and b1-writes needed: distinct arrays;
            // the barrier below fences b0-reads before inv<4> overwrites b0.
            {
                float2 W[4];
                #pragma unroll
                for (int c = 0; c < 4; ++c) {
                    const int k = tid + 256 * c;
                    const float2 z1 = b0[PX(k)];
                    const float2 z2 = b0[PX((NFFT - k) & (NFFT - 1))];
                    if (k == 0) {
                        W[c] = make_float2(0.0f, 0.0f);
                    } else {
                        const int jm = (k < NFFT - k) ? k : NFFT - k;
                        const float2 g = gab[(jm - 1) >> 2];
                        const float Far = 0.5f * (z1.x + z2.x), Fai = 0.5f * (z1.y - z2.y);
                        const float Fbr = 0.5f * (z1.y + z2.y), Fbi = 0.5f * (z2.x - z1.x);
                        W[c] = make_float2(g.x * Far - g.y * Fbi, g.x * Fai + g.y * Fbr);
                    }
                }
                const float t0r = W[0].x + W[2].x, t0i = W[0].y + W[2].y;
                const float t1r = W[0].x - W[2].x, t1i = W[0].y - W[2].y;
                const float t2r = W[1].x + W[3].x, t2i = W[1].y + W[3].y;
                const float ur  = W[1].x - W[3].x, ui  = W[1].y - W[3].y;
                const float t3r = -ui, t3i = ur;           // +i*u (inverse)
                const int d = 4 * tid;
                b1[PX(d)]     = make_float2(t0r + t2r, t0i + t2i);
                b1[PX(d + 1)] = make_float2(t1r + t3r, t1i + t3i);
                b1[PX(d + 2)] = make_float2(t0r - t2r, t0i - t2i);
                b1[PX(d + 3)] = make_float2(t1r - t3r, t1i - t3i);
            }
            __syncthreads();

            // ---- inverse stages NS=4..64 ----
            r4stage2<4,  +1>(b1, b0, tw, tid); __syncthreads();
            r4stage2<16, +1>(b0, b1, tw, tid); __syncthreads();
            r4stage2<64, +1>(b1, b0, tw, tid); __syncthreads();

            // ---- fused inverse stage NS=256 -> r[4], accumulate into s[11] ----
            {
                const float2 c0 = b0[PX(tid)];
                const float2 c1 = b0[PX(tid + 256)];
                const float2 c2 = b0[PX(tid + 512)];
                const float2 c3 = b0[PX(tid + 768)];
                const float2 w = tw[tid];
                const float wr1 = w.x, wi1 = -w.y;         // conjugate (inverse)
                const float wr2 = wr1 * wr1 - wi1 * wi1, wi2 = 2.0f * wr1 * wi1;
                const float wr3 = wr2 * wr1 - wi2 * wi1, wi3 = wr2 * wi1 + wi2 * wr1;
                const float v1r = c1.x * wr1 - c1.y * wi1, v1i = c1.x * wi1 + c1.y * wr1;
                const float v2r = c2.x * wr2 - c2.y * wi2, v2i = c2.x * wi2 + c2.y * wr2;
                const float v3r = c3.x * wr3 - c3.y * wi3, v3i = c3.x * wi3 + c3.y * wr3;
                const float t0r = c0.x + v2r, t0i = c0.y + v2i;
                const float t1r = c0.x - v2r, t1i = c0.y - v2i;
                const float t2r = v1r + v3r,  t2i = v1i + v3i;
                const float ur  = v1r - v3r,  ui  = v1i - v3i;
                const float t3r = -ui, t3i = ur;           // +i*u (inverse)
                float2 r[4];
                r[0] = make_float2(t0r + t2r, t0i + t2i);
                r[1] = make_float2(t1r + t3r, t1i + t3i);
                r[2] = make_float2(t0r - t2r, t0i - t2i);
                r[3] = make_float2(t1r - t3r, t1i - t3i);

                // frame 2pp (Re) -> slot 2pp+c; frame 2pp+1 (Im) -> slot 2pp+1+c
                #pragma unroll
                for (int c = 0; c < 4; ++c) {
                    s[2 * pp + c]     += r[c].x * wv[c];
                    s[2 * pp + 1 + c] += r[c].y * wv[c];
                }
            }
        }
    }

    // ---- epilogue: register-merged OLA ----
    float* ob = out + (size_t)b * NLEN;
    if (blk_interior) {
        #pragma unroll
        for (int c = 0; c < 11; ++c) {
            const int pos = base_blk + tid + 256 * c;
            if (c >= 3 && c <= 7) ob[pos] = s[c];        // block-complete slots
            else atomicAdd(&ob[pos], s[c]);              // shared with 1 neighbor
        }
    } else {
        #pragma unroll
        for (int c = 0; c < 11; ++c) {
            const int pos = base_blk + tid + 256 * c;
            if (pos >= 0 && pos < NLEN) {
                if (c >= 3 && c <= 7) ob[pos] = s[c];
                else atomicAdd(&ob[pos], s[c]);
            }
        }
    }
}

extern "C" void kernel_launch(void* const* d_in, const int* in_sizes, int n_in,
                              void* d_out, int out_size, void* d_ws, size_t ws_size,
                              hipStream_t stream) {
    const float* fb    = (const float*)d_in[0];  // (16,1,128,1001) fp32
    const float* noise = (const float*)d_in[1];  // (16,1,256000)   fp32
    float* out = (float*)d_out;                  // (16,1,256000)   fp32
    float* tbl = (float*)d_ws;                   // 1536 floats = 6 KB

    // Fused zero+tables (out_size = 4,096,000 floats = 1,024,000 float4)
    zero_and_tables<<<2048, 256, 0, stream>>>((float4*)out, out_size / 4, tbl);

    const int grid = BB * QPB;  // 2016 8-frame blocks = 8 XCDs x 252
    fn_kernel<<<grid, 256, 0, stream>>>(fb, noise, tbl, out);
}

// Round 12
// 110.144 us; speedup vs baseline: 1.1120x; 1.1120x over previous
//
#include <hip/hip_runtime.h>
#include <math.h>

#define NFFT   1024
#define HOP    256
#define NBANDS 128
#define TFRM   1001
#define BB     16
#define NLEN   256000   // (T-1)*HOP
#define PADL   512
#define NPAIRS 501      // ceil(1001/2); last pair has no frame_b

// padded LDS index in float2 units: +1 every 16 breaks radix-4 scatter conflicts
#define PX(a) ((a) + ((a) >> 4))

// ---- fused zeroing + table init ----
// out zeroed via float4 grid-stride; tables written by first 1280 global threads.
// ws[0..511] = interleaved (cos,sin) of exp(-2*pi*i*k/1024); ws[512..1535] =
// Hann*(1/1024).
__global__ __launch_bounds__(256) void zero_and_tables(
    float4* __restrict__ out4, int n4, float* __restrict__ ws)
{
    const int tid = blockIdx.x * 256 + threadIdx.x;
    const float4 z = make_float4(0.0f, 0.0f, 0.0f, 0.0f);
    for (int i = tid; i < n4; i += gridDim.x * 256) out4[i] = z;
    if (tid < 256) {
        float s_, c_;
        sincosf(-6.283185307179586f * (float)tid * (1.0f / 1024.0f), &s_, &c_);
        ws[2 * tid]     = c_;
        ws[2 * tid + 1] = s_;
    } else if (tid < 1280) {
        const int k = tid - 256;
        ws[512 + k] = 0.5f * (1.0f - cosf(6.283185307179586f * (float)k * (1.0f / 1023.0f)))
                      * (1.0f / 1024.0f);
    }
}

// One Stockham radix-4 stage on float2 (re,im) LDS data.
// SGN=-1 forward, +1 inverse (conjugate twiddles, +i).
template<int NS, int SGN>
__device__ __forceinline__ void r4stage2(const float2* __restrict__ x,
                                         float2* __restrict__ y,
                                         const float2* __restrict__ tw, int j) {
    const int m = j & (NS - 1);
    const float2 a0 = x[PX(j)];
    const float2 a1 = x[PX(j + 256)];
    const float2 a2 = x[PX(j + 512)];
    const float2 a3 = x[PX(j + 768)];
    float v1r, v1i, v2r, v2i, v3r, v3i;
    {
        const float2 w = tw[m * (256 / NS)];
        const float wr1 = w.x, wi1 = (SGN < 0) ? w.y : -w.y;
        const float wr2 = wr1 * wr1 - wi1 * wi1, wi2 = 2.0f * wr1 * wi1;
        const float wr3 = wr2 * wr1 - wi2 * wi1, wi3 = wr2 * wi1 + wi2 * wr1;
        v1r = a1.x * wr1 - a1.y * wi1; v1i = a1.x * wi1 + a1.y * wr1;
        v2r = a2.x * wr2 - a2.y * wi2; v2i = a2.x * wi2 + a2.y * wr2;
        v3r = a3.x * wr3 - a3.y * wi3; v3i = a3.x * wi3 + a3.y * wr3;
    }
    const float t0r = a0.x + v2r, t0i = a0.y + v2i;
    const float t1r = a0.x - v2r, t1i = a0.y - v2i;
    const float t2r = v1r + v3r,  t2i = v1i + v3i;
    const float ur  = v1r - v3r,  ui  = v1i - v3i;
    const float t3r = (SGN < 0) ? ui  : -ui;
    const float t3i = (SGN < 0) ? -ur : ur;
    const int d = ((j & ~(NS - 1)) << 2) + m;
    y[PX(d)]          = make_float2(t0r + t2r, t0i + t2i);
    y[PX(d + NS)]     = make_float2(t1r + t3r, t1i + t3i);
    y[PX(d + 2*NS)]   = make_float2(t0r - t2r, t0i - t2i);
    y[PX(d + 3*NS)]   = make_float2(t1r - t3r, t1i - t3i);
}

// ---- main kernel: one block (256 threads) per FRAME PAIR ----
// frame_a in Re, frame_b in Im. Fused ends; XCD-chunked swizzle (8016 = 8x1002
// = 2 whole batches per XCD -> OLA atomics + noise reads stay XCD-local in L2;
// round-11 showed shrinking the grid destroys this locality). Interior blocks
// p in [1,498]: 5 unchecked loads + 5 unconditional atomics per thread.
// 9 barriers (Hermitian b0-read / b1-write needs none: distinct arrays, and
// the post-write barrier fences before inv<4> touches either).
__global__ __launch_bounds__(256) void fn_kernel(
    const float* __restrict__ fb,     // (B, 1, 128, T)
    const float* __restrict__ noise,  // (B, 1, NLEN)
    const float* __restrict__ tbl,    // d_ws tables from zero_and_tables
    float* __restrict__ out)          // (B, 1, NLEN), pre-zeroed
{
    __shared__ float2 b0[1087], b1[1087];   // PX(1023)=1086
    __shared__ float2 tw[256];
    __shared__ float2 gab[128];             // (ga, gb) per band

    const int tid = threadIdx.x;
    const int hw  = blockIdx.x;
    const int blk = (hw & 7) * 1002 + (hw >> 3);   // bijective: 8016 = 8*1002
    const int b   = blk / NPAIRS;
    const int p   = blk - b * NPAIRS;
    const int ta  = 2 * p;
    const bool has_b    = (ta + 1) < TFRM;
    const bool interior = (p >= 1) & (p <= 498);   // loads+OLA statically in-bounds

    // twiddles global -> LDS
    tw[tid] = ((const float2*)tbl)[tid & 255];
    // band gains for both frames; adjacent in fb so one thread grabs both
    if (tid < NBANDS) {
        const size_t off = (size_t)b * (NBANDS * TFRM) + (size_t)tid * TFRM + ta;
        const float ga_ = fb[off];
        const float gb_ = has_b ? fb[off + 1] : 0.0f;
        gab[tid] = make_float2(ga_, gb_);
    }

    // ---- fused global load + forward stage 0 (NS=1, no twiddle) ----
    const float* nb = noise + (size_t)b * NLEN;
    const int base = ta * HOP - PADL;
    float2 a0, a1, a2, a3;
    if (interior) {
        // taps are 256 apart == HOP: frame_b reuses frame_a's next tap.
        const int g = base + tid;
        const float v0 = __builtin_fmaf(nb[g],        2.0f, -1.0f);
        const float v1 = __builtin_fmaf(nb[g + 256],  2.0f, -1.0f);
        const float v2 = __builtin_fmaf(nb[g + 512],  2.0f, -1.0f);
        const float v3 = __builtin_fmaf(nb[g + 768],  2.0f, -1.0f);
        const float v4 = __builtin_fmaf(nb[g + 1024], 2.0f, -1.0f);
        a0 = make_float2(v0, v1);
        a1 = make_float2(v1, v2);
        a2 = make_float2(v2, v3);
        a3 = make_float2(v3, v4);
    } else {
        const int g = base + tid;
        #define LD2(gg) make_float2( \
            ((gg) >= 0 && (gg) < NLEN) ? nb[(gg)] * 2.0f - 1.0f : 0.0f, \
            (has_b && (gg) + HOP >= 0 && (gg) + HOP < NLEN) ? nb[(gg) + HOP] * 2.0f - 1.0f : 0.0f)
        a0 = LD2(g); a1 = LD2(g + 256); a2 = LD2(g + 512); a3 = LD2(g + 768);
        #undef LD2
    }
    {
        const float t0r = a0.x + a2.x, t0i = a0.y + a2.y;
        const float t1r = a0.x - a2.x, t1i = a0.y - a2.y;
        const float t2r = a1.x + a3.x, t2i = a1.y + a3.y;
        const float ur  = a1.x - a3.x, ui  = a1.y - a3.y;
        const float t3r = ui, t3i = -ur;           // -i*u (forward)
        const int d = 4 * tid;
        b0[PX(d)]     = make_float2(t0r + t2r, t0i + t2i);
        b0[PX(d + 1)] = make_float2(t1r + t3r, t1i + t3i);
        b0[PX(d + 2)] = make_float2(t0r - t2r, t0i - t2i);
        b0[PX(d + 3)] = make_float2(t1r - t3r, t1i - t3i);
    }
    __syncthreads();

    // ---- forward stages NS=4..256 ----
    r4stage2<4,   -1>(b0, b1, tw, tid); __syncthreads();
    r4stage2<16,  -1>(b1, b0, tw, tid); __syncthreads();
    r4stage2<64,  -1>(b0, b1, tw, tid); __syncthreads();
    r4stage2<256, -1>(b1, b0, tw, tid); __syncthreads();
    // Z in b0, natural order

    // ---- fused Hermitian unpack + filter + inverse stage 0 (NS=1) ----
    // W[k] = ga*Fa + i*gb*Fb, Fa=(Z[k]+conj(Z[N-k]))/2, Fb=-i(Z[k]-conj(Z[N-k]))/2
    // No internal barrier: reads touch only b0, writes only b1 (dead since
    // fwd<256>); the barrier after this block fences b1-writes before inv<4>.
    {
        float2 W[4];
        #pragma unroll
        for (int c = 0; c < 4; ++c) {
            const int k = tid + 256 * c;
            const float2 z1 = b0[PX(k)];
            const float2 z2 = b0[PX((NFFT - k) & (NFFT - 1))];
            if (k == 0) {
                W[c] = make_float2(0.0f, 0.0f);
            } else {
                const int jm = (k < NFFT - k) ? k : NFFT - k;
                const float2 g = gab[(jm - 1) >> 2];
                const float Far = 0.5f * (z1.x + z2.x), Fai = 0.5f * (z1.y - z2.y);
                const float Fbr = 0.5f * (z1.y + z2.y), Fbi = 0.5f * (z2.x - z1.x);
                W[c] = make_float2(g.x * Far - g.y * Fbi, g.x * Fai + g.y * Fbr);
            }
        }
        const float t0r = W[0].x + W[2].x, t0i = W[0].y + W[2].y;
        const float t1r = W[0].x - W[2].x, t1i = W[0].y - W[2].y;
        const float t2r = W[1].x + W[3].x, t2i = W[1].y + W[3].y;
        const float ur  = W[1].x - W[3].x, ui  = W[1].y - W[3].y;
        const float t3r = -ui, t3i = ur;           // +i*u (inverse)
        const int d = 4 * tid;
        b1[PX(d)]     = make_float2(t0r + t2r, t0i + t2i);
        b1[PX(d + 1)] = make_float2(t1r + t3r, t1i + t3i);
        b1[PX(d + 2)] = make_float2(t0r - t2r, t0i - t2i);
        b1[PX(d + 3)] = make_float2(t1r - t3r, t1i - t3i);
    }
    __syncthreads();

    // ---- inverse stages NS=4..64 ----
    r4stage2<4,  +1>(b1, b0, tw, tid); __syncthreads();
    r4stage2<16, +1>(b0, b1, tw, tid); __syncthreads();
    r4stage2<64, +1>(b1, b0, tw, tid); __syncthreads();

    // ---- fused inverse stage NS=256 + window + register-merged overlap-add ----
    {
        const float2 c0 = b0[PX(tid)];
        const float2 c1 = b0[PX(tid + 256)];
        const float2 c2 = b0[PX(tid + 512)];
        const float2 c3 = b0[PX(tid + 768)];
        const float2 w = tw[tid];
        const float wr1 = w.x, wi1 = -w.y;         // conjugate (inverse)
        const float wr2 = wr1 * wr1 - wi1 * wi1, wi2 = 2.0f * wr1 * wi1;
        const float wr3 = wr2 * wr1 - wi2 * wi1, wi3 = wr2 * wi1 + wi2 * wr1;
        const float v1r = c1.x * wr1 - c1.y * wi1, v1i = c1.x * wi1 + c1.y * wr1;
        const float v2r = c2.x * wr2 - c2.y * wi2, v2i = c2.x * wi2 + c2.y * wr2;
        const float v3r = c3.x * wr3 - c3.y * wi3, v3i = c3.x * wi3 + c3.y * wr3;
        const float t0r = c0.x + v2r, t0i = c0.y + v2i;
        const float t1r = c0.x - v2r, t1i = c0.y - v2i;
        const float t2r = v1r + v3r,  t2i = v1i + v3i;
        const float ur  = v1r - v3r,  ui  = v1i - v3i;
        const float t3r = -ui, t3i = ur;           // +i*u (inverse)
        float2 r[4];
        r[0] = make_float2(t0r + t2r, t0i + t2i);
        r[1] = make_float2(t1r + t3r, t1i + t3i);
        r[2] = make_float2(t0r - t2r, t0i - t2i);
        r[3] = make_float2(t1r - t3r, t1i - t3i);

        // frame a sample k=tid+256c -> base+k; frame b sample k -> base+k+256.
        // Thread owns output slots base+tid+256c, c=0..4; merge in registers.
        const float* win = tbl + 512;
        float wv[4];
        #pragma unroll
        for (int c = 0; c < 4; ++c) wv[c] = win[tid + 256 * c];
        float s[5];
        s[0] = r[0].x * wv[0];
        s[1] = r[1].x * wv[1] + r[0].y * wv[0];
        s[2] = r[2].x * wv[2] + r[1].y * wv[1];
        s[3] = r[3].x * wv[3] + r[2].y * wv[2];
        s[4] =                  r[3].y * wv[3];

        float* ob = out + (size_t)b * NLEN;
        if (interior) {
            #pragma unroll
            for (int c = 0; c < 5; ++c) {
                atomicAdd(&ob[base + tid + 256 * c], s[c]);
            }
        } else {
            #pragma unroll
            for (int c = 0; c < 5; ++c) {
                const int pa = base + tid + 256 * c;
                if (pa >= 0 && pa < NLEN) atomicAdd(&ob[pa], s[c]);
            }
        }
    }
}

extern "C" void kernel_launch(void* const* d_in, const int* in_sizes, int n_in,
                              void* d_out, int out_size, void* d_ws, size_t ws_size,
                              hipStream_t stream) {
    const float* fb    = (const float*)d_in[0];  // (16,1,128,1001) fp32
    const float* noise = (const float*)d_in[1];  // (16,1,256000)   fp32
    float* out = (float*)d_out;                  // (16,1,256000)   fp32
    float* tbl = (float*)d_ws;                   // 1536 floats = 6 KB

    // Fused zero+tables (out_size = 4,096,000 floats = 1,024,000 float4)
    zero_and_tables<<<2048, 256, 0, stream>>>((float4*)out, out_size / 4, tbl);

    const int grid = BB * NPAIRS;  // 8016 pair-blocks = 8 XCDs x 1002
    fn_kernel<<<grid, 256, 0, stream>>>(fb, noise, tbl, out);
}